// Round 11
// baseline (2026.005 us; speedup 1.0000x reference)
//
#include <hip/hip_runtime.h>
#include <math.h>

namespace {

typedef float f32x2 __attribute__((ext_vector_type(2)));
typedef float f32x4 __attribute__((ext_vector_type(4)));

#if defined(__has_builtin)
#if __has_builtin(__builtin_elementwise_fma)
#define HAVE_EW_FMA 1
#endif
#endif

__device__ __forceinline__ f32x2 pkfma(f32x2 a, f32x2 b, f32x2 c) {
#ifdef HAVE_EW_FMA
  return __builtin_elementwise_fma(a, b, c);
#else
  return a * b + c;
#endif
}
__device__ __forceinline__ f32x4 fma4(f32x4 a, f32x4 b, f32x4 c) {
#ifdef HAVE_EW_FMA
  return __builtin_elementwise_fma(a, b, c);
#else
  return a * b + c;
#endif
}

constexpr int IMS  = 84;
constexpr int NPIX = IMS * IMS;      // 7056
constexpr int KOBJ = 20;

// ---- workspace layout (float offsets), peak = 27448320 floats = 110 MB ----
constexpr size_t OFF_X    = 0;            // 512*512            -> 262144
constexpr size_t OFF_OT   = 262144;       // 512*40             -> 282624
constexpr size_t OFF_CT   = 282624;       // 512*2 (pad)        -> 283648
constexpr size_t OFF_WT2  = 283648;       // 512*64             -> 316416
constexpr size_t OFF_WT3  = 316416;       // 576*64             -> 353280
constexpr size_t OFF_M0   = 353280;       // 512*10584          -> 5772288
constexpr size_t OFF_R1   = 5772288;      // 512*24*42*42 (R1T) -> 27448320
// H1/H2/FEAT alias into the R1 region (dead before upconv1 writes R1)
constexpr size_t OFF_H1   = OFF_R1;       // 512*32*400         -> 12325888
constexpr size_t OFF_H2   = 12325888;     // 512*64*81          -> 14980096
constexpr size_t OFF_FEAT = 14980096;     // 512*3136           -> 16585728
// fcw split-K partials live in OFF_M0 (dead until the m0 GEMM runs)
// permuted m1w lives in the dead H1 region
constexpr size_t OFF_M1WT = OFF_H1;              // 10584*512 -> +5419008
constexpr size_t OFF_M1BT = OFF_H1 + 5419008;    // 10584     (< OFF_H2)

// ---- generic weight transpose: w[oc][ckk] -> wt[ckk][oc] ----
__global__ void transpose_w(const float* __restrict__ w, float* __restrict__ wt,
                            int OC, int CKK) {
  int idx = blockIdx.x * 256 + threadIdx.x;
  if (idx < OC * CKK) {
    int oc = idx / CKK, ckk = idx % CKK;
    wt[ckk * OC + oc] = w[idx];
  }
}

// ---- permute m1w rows so the m0 GEMM emits [b][y][x][c] directly ----
__global__ __launch_bounds__(128) void permute_m1(
    const float* __restrict__ m1w, const float* __restrict__ m1b,
    float* __restrict__ wT, float* __restrict__ bT) {
  const int n = blockIdx.x;              // 0..10583
  const int c = n / 441, rem = n % 441;
  const int np = rem * 24 + c;
  const float4* src = (const float4*)(m1w + (size_t)n * 512);
  float4* dst = (float4*)(wT + (size_t)np * 512);
  dst[threadIdx.x] = src[threadIdx.x];   // 128 * float4 = 512 floats
  if (threadIdx.x == 0) bT[np] = m1b[n];
}

// ---- conv1: [B,2,84,84] -> [B,32,20,20], k=8 s=4, relu. LDS 44.6 KB ----
__global__ __launch_bounds__(256) void conv1_k(
    const float* __restrict__ inp, const float* __restrict__ w,
    const float* __restrict__ bias, float* __restrict__ out) {
  __shared__ __align__(16) float sIn[NPIX];      // one channel at a time
  __shared__ __align__(16) float sW[128 * 32];   // [c][u][v][oc]
  const int b = blockIdx.x, t = threadIdx.x;
  for (int i = t; i < 4096; i += 256) {
    int oc = i >> 7, ckk = i & 127;
    sW[ckk * 32 + oc] = w[i];
  }
  const float* ip = inp + (size_t)b * 2 * NPIX;
  const int oc0 = (t & 7) * 4;
  const int pg  = t >> 3;
  int ibase[13];
#pragma unroll
  for (int k = 0; k < 13; k++) {
    int p = pg + 32 * k; if (p > 399) p = 399;
    ibase[k] = (p / 20) * 4 * 84 + (p % 20) * 4;
  }
  f32x2 acc[13][2];
#pragma unroll
  for (int k = 0; k < 13; k++) { acc[k][0] = f32x2{0.f, 0.f}; acc[k][1] = f32x2{0.f, 0.f}; }
  for (int c = 0; c < 2; c++) {
    __syncthreads();
    for (int i = t; i < NPIX; i += 256) sIn[i] = ip[c * NPIX + i];
    __syncthreads();
    for (int u = 0; u < 8; u++) {
#pragma unroll
      for (int v = 0; v < 8; v++) {
        const float4 wv = *(const float4*)&sW[((c * 8 + u) * 8 + v) * 32 + oc0];
        const f32x2 w0 = {wv.x, wv.y}, w1 = {wv.z, wv.w};
        const int off = u * 84 + v;
#pragma unroll
        for (int k = 0; k < 13; k++) {
          float x = sIn[off + ibase[k]];
          f32x2 xv = {x, x};
          acc[k][0] = pkfma(w0, xv, acc[k][0]);
          acc[k][1] = pkfma(w1, xv, acc[k][1]);
        }
      }
    }
  }
  float b0 = bias[oc0], b1 = bias[oc0+1], b2 = bias[oc0+2], b3 = bias[oc0+3];
  float* op = out + (size_t)b * 32 * 400;
#pragma unroll
  for (int k = 0; k < 13; k++) {
    int p = pg + 32 * k;
    if (p < 400) {
      op[(oc0+0)*400 + p] = fmaxf(acc[k][0][0] + b0, 0.f);
      op[(oc0+1)*400 + p] = fmaxf(acc[k][0][1] + b1, 0.f);
      op[(oc0+2)*400 + p] = fmaxf(acc[k][1][0] + b2, 0.f);
      op[(oc0+3)*400 + p] = fmaxf(acc[k][1][1] + b3, 0.f);
    }
  }
}

// ---- conv2: [B,32,20,20] -> [B,64,9,9], k=4 s=2, relu. LDS 51.2 KB ----
__global__ __launch_bounds__(256) void conv2_k(
    const float* __restrict__ in, const float* __restrict__ wt,
    const float* __restrict__ bias, float* __restrict__ out) {
  __shared__ float sIn[32 * 400];
  const int b = blockIdx.x, t = threadIdx.x;
  const float* ip = in + (size_t)b * 12800;
  for (int i = t; i < 12800; i += 256) sIn[i] = ip[i];
  __syncthreads();
  const int oc0 = (t & 7) * 8;
  const int pg  = t >> 3;
  int base[3];
#pragma unroll
  for (int k = 0; k < 3; k++) {
    int p = pg + 32 * k; if (p > 80) p = 80;
    base[k] = (p / 9) * 40 + (p % 9) * 2;
  }
  f32x2 acc[3][4];
#pragma unroll
  for (int k = 0; k < 3; k++)
#pragma unroll
    for (int o = 0; o < 4; o++) acc[k][o] = f32x2{0.f, 0.f};
  for (int c = 0; c < 32; c++) {
#pragma unroll
    for (int u = 0; u < 4; u++)
#pragma unroll
      for (int v = 0; v < 4; v++) {
        const float* wp = wt + ((c * 4 + u) * 4 + v) * 64 + oc0;
        float4 wa = *(const float4*)wp;
        float4 wb = *(const float4*)(wp + 4);
        const f32x2 w0 = {wa.x, wa.y}, w1 = {wa.z, wa.w};
        const f32x2 w2 = {wb.x, wb.y}, w3 = {wb.z, wb.w};
        int off = c * 400 + u * 20 + v;
#pragma unroll
        for (int k = 0; k < 3; k++) {
          float x = sIn[off + base[k]];
          f32x2 xv = {x, x};
          acc[k][0] = pkfma(w0, xv, acc[k][0]);
          acc[k][1] = pkfma(w1, xv, acc[k][1]);
          acc[k][2] = pkfma(w2, xv, acc[k][2]);
          acc[k][3] = pkfma(w3, xv, acc[k][3]);
        }
      }
  }
  float* op = out + (size_t)b * 5184;
#pragma unroll
  for (int k = 0; k < 3; k++) {
    int p = pg + 32 * k;
    if (p < 81) {
#pragma unroll
      for (int o = 0; o < 8; o++)
        op[(oc0+o)*81 + p] = fmaxf(acc[k][o >> 1][o & 1] + bias[oc0+o], 0.f);
    }
  }
}

// ---- conv3: [B,64,9,9] -> feat [B,3136] (= [64][7][7] flat), k=3 s=1, relu ----
__global__ __launch_bounds__(256) void conv3_k(
    const float* __restrict__ in, const float* __restrict__ wt,
    const float* __restrict__ bias, float* __restrict__ out) {
  __shared__ float sIn[64 * 81];
  const int b = blockIdx.x, t = threadIdx.x;
  const float* ip = in + (size_t)b * 5184;
  for (int i = t; i < 5184; i += 256) sIn[i] = ip[i];
  __syncthreads();
  const int oc0 = (t & 7) * 8;
  const int pg  = t >> 3;
  int base[2];
#pragma unroll
  for (int k = 0; k < 2; k++) {
    int p = pg + 32 * k; if (p > 48) p = 48;
    base[k] = (p / 7) * 9 + (p % 7);
  }
  f32x2 acc[2][4];
#pragma unroll
  for (int k = 0; k < 2; k++)
#pragma unroll
    for (int o = 0; o < 4; o++) acc[k][o] = f32x2{0.f, 0.f};
  for (int c = 0; c < 64; c++) {
#pragma unroll
    for (int u = 0; u < 3; u++)
#pragma unroll
      for (int v = 0; v < 3; v++) {
        const float* wp = wt + ((c * 3 + u) * 3 + v) * 64 + oc0;
        float4 wa = *(const float4*)wp;
        float4 wb = *(const float4*)(wp + 4);
        const f32x2 w0 = {wa.x, wa.y}, w1 = {wa.z, wa.w};
        const f32x2 w2 = {wb.x, wb.y}, w3 = {wb.z, wb.w};
        int off = c * 81 + u * 9 + v;
#pragma unroll
        for (int k = 0; k < 2; k++) {
          float x = sIn[off + base[k]];
          f32x2 xv = {x, x};
          acc[k][0] = pkfma(w0, xv, acc[k][0]);
          acc[k][1] = pkfma(w1, xv, acc[k][1]);
          acc[k][2] = pkfma(w2, xv, acc[k][2]);
          acc[k][3] = pkfma(w3, xv, acc[k][3]);
        }
      }
  }
  float* op = out + (size_t)b * 3136;
#pragma unroll
  for (int k = 0; k < 2; k++) {
    int p = pg + 32 * k;
    if (p < 49) {
#pragma unroll
      for (int o = 0; o < 8; o++)
        op[(oc0+o)*49 + p] = fmaxf(acc[k][o >> 1][o & 1] + bias[oc0+o], 0.f);
    }
  }
}

// ---- GEMM 64x64 tile: C[M,N] = A[M,K] @ W[N,K]^T + bias, optional relu ----
template<bool RELU>
__global__ __launch_bounds__(256) void gemm_k(
    const float* __restrict__ A, const float* __restrict__ Wm,
    const float* __restrict__ bias, float* __restrict__ C,
    int N, int K) {
  __shared__ __align__(16) float As[16][68];
  __shared__ __align__(16) float Ws[16][68];
  const int t = threadIdx.x;
  const int m0 = blockIdx.y * 64, n0 = blockIdx.x * 64;
  const int r  = t >> 2;
  const int kq = (t & 3) * 4;
  const int r0 = (t >> 4) * 4, c0 = (t & 15) * 4;
  f32x2 acc[4][2];
#pragma unroll
  for (int i = 0; i < 4; i++) { acc[i][0] = f32x2{0.f, 0.f}; acc[i][1] = f32x2{0.f, 0.f}; }
  for (int k0 = 0; k0 < K; k0 += 16) {
    float4 a = *(const float4*)(A + (size_t)(m0 + r) * K + k0 + kq);
    int wrow = n0 + r;
    float4 wv = make_float4(0.f, 0.f, 0.f, 0.f);
    if (wrow < N) wv = *(const float4*)(Wm + (size_t)wrow * K + k0 + kq);
    __syncthreads();
    As[kq+0][r] = a.x; As[kq+1][r] = a.y; As[kq+2][r] = a.z; As[kq+3][r] = a.w;
    Ws[kq+0][r] = wv.x; Ws[kq+1][r] = wv.y; Ws[kq+2][r] = wv.z; Ws[kq+3][r] = wv.w;
    __syncthreads();
#pragma unroll
    for (int kk = 0; kk < 16; kk++) {
      float4 av = *(const float4*)&As[kk][r0];
      float4 bv = *(const float4*)&Ws[kk][c0];
      const f32x2 b0 = {bv.x, bv.y}, b1 = {bv.z, bv.w};
      float ar[4] = {av.x, av.y, av.z, av.w};
#pragma unroll
      for (int i = 0; i < 4; i++) {
        f32x2 ai = {ar[i], ar[i]};
        acc[i][0] = pkfma(b0, ai, acc[i][0]);
        acc[i][1] = pkfma(b1, ai, acc[i][1]);
      }
    }
  }
#pragma unroll
  for (int i = 0; i < 4; i++) {
    int row = m0 + r0 + i;
#pragma unroll
    for (int j = 0; j < 4; j++) {
      int col = n0 + c0 + j;
      if (col < N) {
        float v = acc[i][j >> 1][j & 1] + bias[col];
        C[(size_t)row * N + col] = RELU ? fmaxf(v, 0.f) : v;
      }
    }
  }
}

// ---- split-K GEMM (no bias/relu): Cpart[z][M][N] partial over K-slice ----
__global__ __launch_bounds__(256) void gemm_splitk_k(
    const float* __restrict__ A, const float* __restrict__ Wm,
    float* __restrict__ Cpart, int N, int K, int Kslice) {
  __shared__ __align__(16) float As[16][68];
  __shared__ __align__(16) float Ws[16][68];
  const int t = threadIdx.x;
  const int m0 = blockIdx.y * 64, n0 = blockIdx.x * 64;
  const int kbeg = blockIdx.z * Kslice;
  const int kend = kbeg + Kslice;
  const int r  = t >> 2;
  const int kq = (t & 3) * 4;
  const int r0 = (t >> 4) * 4, c0 = (t & 15) * 4;
  f32x2 acc[4][2];
#pragma unroll
  for (int i = 0; i < 4; i++) { acc[i][0] = f32x2{0.f, 0.f}; acc[i][1] = f32x2{0.f, 0.f}; }
  for (int k0 = kbeg; k0 < kend; k0 += 16) {
    float4 a = *(const float4*)(A + (size_t)(m0 + r) * K + k0 + kq);
    float4 wv = *(const float4*)(Wm + (size_t)(n0 + r) * K + k0 + kq);
    __syncthreads();
    As[kq+0][r] = a.x; As[kq+1][r] = a.y; As[kq+2][r] = a.z; As[kq+3][r] = a.w;
    Ws[kq+0][r] = wv.x; Ws[kq+1][r] = wv.y; Ws[kq+2][r] = wv.z; Ws[kq+3][r] = wv.w;
    __syncthreads();
#pragma unroll
    for (int kk = 0; kk < 16; kk++) {
      float4 av = *(const float4*)&As[kk][r0];
      float4 bv = *(const float4*)&Ws[kk][c0];
      const f32x2 b0 = {bv.x, bv.y}, b1 = {bv.z, bv.w};
      float ar[4] = {av.x, av.y, av.z, av.w};
#pragma unroll
      for (int i = 0; i < 4; i++) {
        f32x2 ai = {ar[i], ar[i]};
        acc[i][0] = pkfma(b0, ai, acc[i][0]);
        acc[i][1] = pkfma(b1, ai, acc[i][1]);
      }
    }
  }
  float* cp = Cpart + (size_t)blockIdx.z * 512 * 512;
#pragma unroll
  for (int i = 0; i < 4; i++) {
    int row = m0 + r0 + i;
#pragma unroll
    for (int j = 0; j < 4; j++)
      cp[(size_t)row * N + n0 + c0 + j] = acc[i][j >> 1][j & 1];
  }
}

// ---- reduce 4 split-K partials + bias + relu -> X [512][512] ----
__global__ __launch_bounds__(256) void splitk_reduce_k(
    const float* __restrict__ Cpart, const float* __restrict__ bias,
    float* __restrict__ X) {
  int i4 = blockIdx.x * 256 + threadIdx.x;     // float4 index over 512*512/4
  if (i4 < 65536) {
    int col4 = (i4 & 127) * 4;
    float4 p0 = *(const float4*)&Cpart[(size_t)i4 * 4];
    float4 p1 = *(const float4*)&Cpart[262144 + (size_t)i4 * 4];
    float4 p2 = *(const float4*)&Cpart[524288 + (size_t)i4 * 4];
    float4 p3 = *(const float4*)&Cpart[786432 + (size_t)i4 * 4];
    float4 bb = *(const float4*)&bias[col4];
    float4 o;
    o.x = fmaxf(p0.x + p1.x + p2.x + p3.x + bb.x, 0.f);
    o.y = fmaxf(p0.y + p1.y + p2.y + p3.y + bb.y, 0.f);
    o.z = fmaxf(p0.z + p1.z + p2.z + p3.z + bb.z, 0.f);
    o.w = fmaxf(p0.w + p1.w + p2.w + p3.w + bb.w, 0.f);
    *(float4*)&X[(size_t)i4 * 4] = o;
  }
}

// ---- GEMM 128x128 tile, 8x8/thread (for large-N m0 matmul). No relu. ----
__global__ __launch_bounds__(256) void gemm128_k(
    const float* __restrict__ A, const float* __restrict__ Wm,
    const float* __restrict__ bias, float* __restrict__ C,
    int N, int K) {
  __shared__ __align__(16) float As[16][132];
  __shared__ __align__(16) float Ws[16][132];
  const int t = threadIdx.x;
  const int m0 = blockIdx.y * 128, n0 = blockIdx.x * 128;
  const int lr = t >> 1;            // 0..127 staging row
  const int kq = (t & 1) * 8;       // 0 or 8
  const int r0 = (t >> 4) * 8, c0 = (t & 15) * 8;
  f32x2 acc[8][4];
#pragma unroll
  for (int i = 0; i < 8; i++)
#pragma unroll
    for (int j = 0; j < 4; j++) acc[i][j] = f32x2{0.f, 0.f};
  for (int k0 = 0; k0 < K; k0 += 16) {
    const float* ap = A + (size_t)(m0 + lr) * K + k0 + kq;
    float4 a0 = *(const float4*)ap;
    float4 a1 = *(const float4*)(ap + 4);
    int wrow = n0 + lr;
    float4 w0 = make_float4(0.f,0.f,0.f,0.f), w1 = make_float4(0.f,0.f,0.f,0.f);
    if (wrow < N) {
      const float* wp = Wm + (size_t)wrow * K + k0 + kq;
      w0 = *(const float4*)wp;
      w1 = *(const float4*)(wp + 4);
    }
    __syncthreads();
    As[kq+0][lr] = a0.x; As[kq+1][lr] = a0.y; As[kq+2][lr] = a0.z; As[kq+3][lr] = a0.w;
    As[kq+4][lr] = a1.x; As[kq+5][lr] = a1.y; As[kq+6][lr] = a1.z; As[kq+7][lr] = a1.w;
    Ws[kq+0][lr] = w0.x; Ws[kq+1][lr] = w0.y; Ws[kq+2][lr] = w0.z; Ws[kq+3][lr] = w0.w;
    Ws[kq+4][lr] = w1.x; Ws[kq+5][lr] = w1.y; Ws[kq+6][lr] = w1.z; Ws[kq+7][lr] = w1.w;
    __syncthreads();
#pragma unroll
    for (int kk = 0; kk < 16; kk++) {
      float4 av0 = *(const float4*)&As[kk][r0];
      float4 av1 = *(const float4*)&As[kk][r0 + 4];
      float4 bv0 = *(const float4*)&Ws[kk][c0];
      float4 bv1 = *(const float4*)&Ws[kk][c0 + 4];
      float ar[8] = {av0.x, av0.y, av0.z, av0.w, av1.x, av1.y, av1.z, av1.w};
      f32x2 br[4] = {{bv0.x, bv0.y}, {bv0.z, bv0.w}, {bv1.x, bv1.y}, {bv1.z, bv1.w}};
#pragma unroll
      for (int i = 0; i < 8; i++) {
        f32x2 ai = {ar[i], ar[i]};
#pragma unroll
        for (int j = 0; j < 4; j++) acc[i][j] = pkfma(br[j], ai, acc[i][j]);
      }
    }
  }
#pragma unroll
  for (int i = 0; i < 8; i++) {
    int row = m0 + r0 + i;
#pragma unroll
    for (int j = 0; j < 8; j++) {
      int col = n0 + c0 + j;
      if (col < N)
        C[(size_t)row * N + col] = acc[i][j >> 1][j & 1] + bias[col];
    }
  }
}

// ---- upconv1: upsample 21->42 + residual 3x3 conv + relu.
//      Conv: thread = (oc-half, pixel-pair, col): 12 oc x 2 adjacent rows.
//      Weight VMEM /4 per pixel (f32x4 loads serve 2 px).  Output
//      channel-last [b][42][42][24]; each thread stores 3xb128 per px. ----
__global__ __launch_bounds__(384, 6) void upconv1_k(
    const float* __restrict__ X, const float* __restrict__ wt,
    const float* __restrict__ bias, float* __restrict__ outT) {
  constexpr int S_IN = 21, S_OUT = 42, TR = 6, UH = 8, UW = 44, NTILE = 7;
  __shared__ __align__(16) float sU[24 * UH * UW];   // 8448 floats = 33 KB
  const int b = blockIdx.x / NTILE;
  const int y0 = (blockIdx.x % NTILE) * TR;
  const int t = threadIdx.x;
  const float* xb = X + (size_t)b * 24 * S_IN * S_IN;   // [21][21][24]
  const float sc = (float)(S_IN - 1) / (float)(S_OUT - 1);
  for (int rr = t; rr < UH * UW; rr += 384) {
    const int ry = rr / UW, cx = rr % UW;
    const int y = y0 + ry - 1, x = cx - 1;
    float* sdst = &sU[rr];
    if (y >= 0 && y < S_OUT && x >= 0 && x < S_OUT) {
      float py = y * sc, px = x * sc;
      int ly = (int)py; if (ly > S_IN - 2) ly = S_IN - 2;
      int lx = (int)px; if (lx > S_IN - 2) lx = S_IN - 2;
      float wy = py - (float)ly, wx = px - (float)lx;
      const f32x4 wx4 = {wx, wx, wx, wx};
      const f32x4 wy4 = {wy, wy, wy, wy};
      const float* p00 = xb + ((size_t)ly * S_IN + lx) * 24;
#pragma unroll
      for (int g = 0; g < 6; g++) {
        f32x4 q00 = *(const f32x4*)(p00 + 4 * g);
        f32x4 q01 = *(const f32x4*)(p00 + 24 + 4 * g);
        f32x4 q10 = *(const f32x4*)(p00 + 24 * S_IN + 4 * g);
        f32x4 q11 = *(const f32x4*)(p00 + 24 * S_IN + 24 + 4 * g);
        f32x4 ht = fma4(wx4, q01 - q00, q00);
        f32x4 hb = fma4(wx4, q11 - q10, q10);
        f32x4 v  = fma4(wy4, hb - ht, ht);
        sdst[(4*g + 0) * UH * UW] = v[0];
        sdst[(4*g + 1) * UH * UW] = v[1];
        sdst[(4*g + 2) * UH * UW] = v[2];
        sdst[(4*g + 3) * UH * UW] = v[3];
      }
    } else {
#pragma unroll
      for (int c = 0; c < 24; c++) sdst[c * UH * UW] = 0.f;
    }
  }
  __syncthreads();
  if (t < 252) {
    const int h = t & 1;            // oc-half
    const int u = t >> 1;           // 0..125
    const int lx = u % 42, q = u / 42;
    const int pr0 = 2 * q, pr1 = pr0 + 1;
    f32x2 a0[6], a1[6];
#pragma unroll
    for (int j = 0; j < 6; j++) { a0[j] = f32x2{0.f, 0.f}; a1[j] = f32x2{0.f, 0.f}; }
    const float* wph = wt + h * 12;
    for (int ic = 0; ic < 24; ic++) {
      const float* ub = &sU[(ic * UH + pr0) * UW + lx];
      float v[4][3];
#pragma unroll
      for (int r = 0; r < 4; r++)
#pragma unroll
        for (int kx = 0; kx < 3; kx++)
          v[r][kx] = ub[r * UW + kx];
      const float* wpc = wph + ic * 216;
#pragma unroll
      for (int ky = 0; ky < 3; ky++)
#pragma unroll
        for (int kx = 0; kx < 3; kx++) {
          const float* wp = wpc + (ky * 3 + kx) * 24;
          const f32x4 wA = *(const f32x4*)wp;
          const f32x4 wB = *(const f32x4*)(wp + 4);
          const f32x4 wC = *(const f32x4*)(wp + 8);
          const f32x2 w0 = {wA[0], wA[1]}, w1 = {wA[2], wA[3]};
          const f32x2 w2 = {wB[0], wB[1]}, w3 = {wB[2], wB[3]};
          const f32x2 w4 = {wC[0], wC[1]}, w5 = {wC[2], wC[3]};
          const f32x2 X0 = {v[ky][kx], v[ky][kx]};
          const f32x2 X1 = {v[ky + 1][kx], v[ky + 1][kx]};
          a0[0] = pkfma(w0, X0, a0[0]); a1[0] = pkfma(w0, X1, a1[0]);
          a0[1] = pkfma(w1, X0, a0[1]); a1[1] = pkfma(w1, X1, a1[1]);
          a0[2] = pkfma(w2, X0, a0[2]); a1[2] = pkfma(w2, X1, a1[2]);
          a0[3] = pkfma(w3, X0, a0[3]); a1[3] = pkfma(w3, X1, a1[3]);
          a0[4] = pkfma(w4, X0, a0[4]); a1[4] = pkfma(w4, X1, a1[4]);
          a0[5] = pkfma(w5, X0, a0[5]); a1[5] = pkfma(w5, X1, a1[5]);
        }
    }
    const int cb = h * 12;
    const f32x4 bb0 = *(const f32x4*)&bias[cb];
    const f32x4 bb1 = *(const f32x4*)&bias[cb + 4];
    const f32x4 bb2 = *(const f32x4*)&bias[cb + 8];
#pragma unroll
    for (int px = 0; px < 2; px++) {
      const int pr = px ? pr1 : pr0;
      const f32x2* aa = px ? a1 : a0;
      float o[12];
#pragma unroll
      for (int j = 0; j < 6; j++) {
        float c0v = sU[((cb + 2*j)     * UH + pr + 1) * UW + lx + 1];
        float c1v = sU[((cb + 2*j + 1) * UH + pr + 1) * UW + lx + 1];
        o[2*j]   = c0v + aa[j][0];
        o[2*j+1] = c1v + aa[j][1];
      }
      float* orow = outT + ((size_t)b * 1764 + (y0 + pr) * 42 + lx) * 24 + cb;
      f32x4 s0 = {o[0], o[1], o[2], o[3]};   s0 += bb0;
      f32x4 s1 = {o[4], o[5], o[6], o[7]};   s1 += bb1;
      f32x4 s2 = {o[8], o[9], o[10], o[11]}; s2 += bb2;
#pragma unroll
      for (int e = 0; e < 4; e++) {
        s0[e] = fmaxf(s0[e], 0.f); s1[e] = fmaxf(s1[e], 0.f); s2[e] = fmaxf(s2[e], 0.f);
      }
      *(f32x4*)(orow)     = s0;
      *(f32x4*)(orow + 4) = s1;
      *(f32x4*)(orow + 8) = s2;
    }
  }
}

// ---- fused: upsample 42->84 + residual conv + relu + 1x1 conv + sigmoid
//      + flow + bilinear warp.  Same oc-half x pixel-pair conv; the
//      24-channel 1x1 dot completes via __shfl_xor (oc-halves are
//      adjacent lanes).  Lane h==0 stores. ----
__global__ __launch_bounds__(384, 6) void upconv2_final_k(
    const float* __restrict__ R1T, const float* __restrict__ inp,
    const float* __restrict__ wt, const float* __restrict__ bias,
    const float* __restrict__ c3w, const float* __restrict__ c3b,
    const float* __restrict__ ot, const float* __restrict__ ct,
    float* __restrict__ out) {
  constexpr int S_IN = 42, S_OUT = 84, TR = 6, UH = 8, TW = 42, UW = 44;
  __shared__ __align__(16) float sU[24 * UH * UW];   // 8448 floats = 33 KB
  const int blk = blockIdx.x;
  const int b = blk / 28;
  const int rr0 = blk % 28;
  const int y0 = (rr0 >> 1) * TR;
  const int x0 = (rr0 & 1) * TW;
  const int t = threadIdx.x;
  const float* xb = R1T + (size_t)b * 1764 * 24;   // [42][42][24]
  const float sc = (float)(S_IN - 1) / (float)(S_OUT - 1);
  for (int rr = t; rr < UH * UW; rr += 384) {
    const int ry = rr / UW, cx = rr % UW;
    const int y = y0 + ry - 1, x = x0 + cx - 1;
    float* sdst = &sU[rr];
    if (y >= 0 && y < S_OUT && x >= 0 && x < S_OUT) {
      float py = y * sc, px = x * sc;
      int ly = (int)py; if (ly > S_IN - 2) ly = S_IN - 2;
      int lx = (int)px; if (lx > S_IN - 2) lx = S_IN - 2;
      float wy = py - (float)ly, wx = px - (float)lx;
      const f32x4 wx4 = {wx, wx, wx, wx};
      const f32x4 wy4 = {wy, wy, wy, wy};
      const float* p00 = xb + ((size_t)ly * S_IN + lx) * 24;
#pragma unroll
      for (int g = 0; g < 6; g++) {
        f32x4 q00 = *(const f32x4*)(p00 + 4 * g);
        f32x4 q01 = *(const f32x4*)(p00 + 24 + 4 * g);
        f32x4 q10 = *(const f32x4*)(p00 + 24 * S_IN + 4 * g);
        f32x4 q11 = *(const f32x4*)(p00 + 24 * S_IN + 24 + 4 * g);
        f32x4 ht = fma4(wx4, q01 - q00, q00);
        f32x4 hb = fma4(wx4, q11 - q10, q10);
        f32x4 v  = fma4(wy4, hb - ht, ht);
        sdst[(4*g + 0) * UH * UW] = v[0];
        sdst[(4*g + 1) * UH * UW] = v[1];
        sdst[(4*g + 2) * UH * UW] = v[2];
        sdst[(4*g + 3) * UH * UW] = v[3];
      }
    } else {
#pragma unroll
      for (int c = 0; c < 24; c++) sdst[c * UH * UW] = 0.f;
    }
  }
  __syncthreads();
  if (t < 252) {
    const int h = t & 1;            // oc-half (adjacent lanes pair up)
    const int u = t >> 1;           // 0..125
    const int lx = u % 42, q = u / 42;
    const int pr0 = 2 * q, pr1 = pr0 + 1;
    f32x2 a0[6], a1[6];
#pragma unroll
    for (int j = 0; j < 6; j++) { a0[j] = f32x2{0.f, 0.f}; a1[j] = f32x2{0.f, 0.f}; }
    const float* wph = wt + h * 12;
    for (int ic = 0; ic < 24; ic++) {
      const float* ub = &sU[(ic * UH + pr0) * UW + lx];
      float v[4][3];
#pragma unroll
      for (int r = 0; r < 4; r++)
#pragma unroll
        for (int kx = 0; kx < 3; kx++)
          v[r][kx] = ub[r * UW + kx];
      const float* wpc = wph + ic * 216;
#pragma unroll
      for (int ky = 0; ky < 3; ky++)
#pragma unroll
        for (int kx = 0; kx < 3; kx++) {
          const float* wp = wpc + (ky * 3 + kx) * 24;
          const f32x4 wA = *(const f32x4*)wp;
          const f32x4 wB = *(const f32x4*)(wp + 4);
          const f32x4 wC = *(const f32x4*)(wp + 8);
          const f32x2 w0 = {wA[0], wA[1]}, w1 = {wA[2], wA[3]};
          const f32x2 w2 = {wB[0], wB[1]}, w3 = {wB[2], wB[3]};
          const f32x2 w4 = {wC[0], wC[1]}, w5 = {wC[2], wC[3]};
          const f32x2 X0 = {v[ky][kx], v[ky][kx]};
          const f32x2 X1 = {v[ky + 1][kx], v[ky + 1][kx]};
          a0[0] = pkfma(w0, X0, a0[0]); a1[0] = pkfma(w0, X1, a1[0]);
          a0[1] = pkfma(w1, X0, a0[1]); a1[1] = pkfma(w1, X1, a1[1]);
          a0[2] = pkfma(w2, X0, a0[2]); a1[2] = pkfma(w2, X1, a1[2]);
          a0[3] = pkfma(w3, X0, a0[3]); a1[3] = pkfma(w3, X1, a1[3]);
          a0[4] = pkfma(w4, X0, a0[4]); a1[4] = pkfma(w4, X1, a1[4]);
          a0[5] = pkfma(w5, X0, a0[5]); a1[5] = pkfma(w5, X1, a1[5]);
        }
    }
    // residual + relu (12 channels x 2 px, in register pairs)
    const int cb = h * 12;
    f32x2 r0[6], r1[6];
#pragma unroll
    for (int j = 0; j < 6; j++) {
      f32x2 b2 = *(const f32x2*)&bias[cb + 2*j];
      f32x2 u0 = { sU[((cb + 2*j)     * UH + pr0 + 1) * UW + lx + 1],
                   sU[((cb + 2*j + 1) * UH + pr0 + 1) * UW + lx + 1] };
      f32x2 u1 = { sU[((cb + 2*j)     * UH + pr1 + 1) * UW + lx + 1],
                   sU[((cb + 2*j + 1) * UH + pr1 + 1) * UW + lx + 1] };
      f32x2 s0 = u0 + a0[j] + b2;
      f32x2 s1 = u1 + a1[j] + b2;
      r0[j][0] = fmaxf(s0[0], 0.f); r0[j][1] = fmaxf(s0[1], 0.f);
      r1[j][0] = fmaxf(s1[0], 0.f); r1[j][1] = fmaxf(s1[1], 0.f);
    }
    // 1x1 conv (half-dot) + shfl-combine + sigmoid + flow
    float fy0 = ct[b * 2], fx0 = ct[b * 2 + 1];
    float fy1 = fy0, fx1 = fx0;
    const float* cwh = c3w + cb;
    for (int k = 0; k < KOBJ; k++) {
      const f32x4 cA = *(const f32x4*)(cwh + k * 24);
      const f32x4 cB = *(const f32x4*)(cwh + k * 24 + 4);
      const f32x4 cC = *(const f32x4*)(cwh + k * 24 + 8);
      const f32x2 c0 = {cA[0], cA[1]}, c1 = {cA[2], cA[3]};
      const f32x2 c2 = {cB[0], cB[1]}, c3 = {cB[2], cB[3]};
      const f32x2 c4 = {cC[0], cC[1]}, c5 = {cC[2], cC[3]};
      f32x2 z0v = r0[0] * c0; f32x2 z1v = r1[0] * c0;
      z0v = pkfma(r0[1], c1, z0v); z1v = pkfma(r1[1], c1, z1v);
      z0v = pkfma(r0[2], c2, z0v); z1v = pkfma(r1[2], c2, z1v);
      z0v = pkfma(r0[3], c3, z0v); z1v = pkfma(r1[3], c3, z1v);
      z0v = pkfma(r0[4], c4, z0v); z1v = pkfma(r1[4], c4, z1v);
      z0v = pkfma(r0[5], c5, z0v); z1v = pkfma(r1[5], c5, z1v);
      float z0 = z0v[0] + z0v[1];
      float z1 = z1v[0] + z1v[1];
      z0 += __shfl_xor(z0, 1);          // combine the two oc-halves
      z1 += __shfl_xor(z1, 1);
      z0 += c3b[k]; z1 += c3b[k];
      float m0 = 1.f / (1.f + __expf(-z0));
      float m1 = 1.f / (1.f + __expf(-z1));
      float oy = ot[b * 2 * KOBJ + 2 * k], ox = ot[b * 2 * KOBJ + 2 * k + 1];
      fy0 += m0 * oy; fx0 += m0 * ox;
      fy1 += m1 * oy; fx1 += m1 * ox;
    }
    if (h == 0) {
      const float imgf = 0.01f * 84.0f;
      const float* src = inp + ((size_t)b * 2 + 1) * NPIX;
#pragma unroll
      for (int px = 0; px < 2; px++) {
        const int pr = px ? pr1 : pr0;
        const float fy = px ? fy1 : fy0;
        const float fx = px ? fx1 : fx0;
        const int gy = y0 + pr, gx = x0 + lx;
        float ys = imgf * fy + (float)gy;
        float xs = imgf * fx + (float)gx;
        int ix0 = (int)floorf(xs); ix0 = ix0 < 0 ? 0 : (ix0 > 83 ? 83 : ix0);
        int iy0 = (int)floorf(ys); iy0 = iy0 < 0 ? 0 : (iy0 > 83 ? 83 : iy0);
        int ix1 = ix0 + 1 > 83 ? 83 : ix0 + 1;
        int iy1 = iy0 + 1 > 83 ? 83 : iy0 + 1;
        float xc = fminf(fmaxf(xs, 0.f), 83.f);
        float yc = fminf(fmaxf(ys, 0.f), 83.f);
        float wx1 = (float)ix1 - xc, wx0 = xc - (float)ix0;
        float wy1 = (float)iy1 - yc, wy0 = yc - (float)iy0;
        float Ia = src[iy0 * 84 + ix0], Ib = src[iy1 * 84 + ix0];
        float Ic = src[iy0 * 84 + ix1], Id = src[iy1 * 84 + ix1];
        out[(size_t)b * NPIX + gy * 84 + gx] =
            wx1 * wy1 * Ia + wx1 * wy0 * Ib + wx0 * wy1 * Ic + wx0 * wy0 * Id;
      }
    }
  }
}

}  // namespace

extern "C" void kernel_launch(void* const* d_in, const int* in_sizes, int n_in,
                              void* d_out, int out_size, void* d_ws, size_t ws_size,
                              hipStream_t stream) {
  const float* inp = (const float*)d_in[0];
  const float* cw1 = (const float*)d_in[1];
  const float* cb1 = (const float*)d_in[2];
  const float* cw2 = (const float*)d_in[3];
  const float* cb2 = (const float*)d_in[4];
  const float* cw3 = (const float*)d_in[5];
  const float* cb3 = (const float*)d_in[6];
  const float* fcw = (const float*)d_in[7];
  const float* fcb = (const float*)d_in[8];
  const float* otw = (const float*)d_in[9];
  const float* otb = (const float*)d_in[10];
  const float* ctw = (const float*)d_in[11];
  const float* ctb = (const float*)d_in[12];
  const float* m1w = (const float*)d_in[13];
  const float* m1b = (const float*)d_in[14];
  const float* c1w = (const float*)d_in[15];
  const float* c1b = (const float*)d_in[16];
  const float* c2w = (const float*)d_in[17];
  const float* c2b = (const float*)d_in[18];
  const float* c3w = (const float*)d_in[19];
  const float* c3b = (const float*)d_in[20];
  float* W = (float*)d_ws;
  float* out = (float*)d_out;

  transpose_w<<<(64 * 512 + 255) / 256, 256, 0, stream>>>(cw2, W + OFF_WT2, 64, 512);
  transpose_w<<<(64 * 576 + 255) / 256, 256, 0, stream>>>(cw3, W + OFF_WT3, 64, 576);
  conv1_k<<<512, 256, 0, stream>>>(inp, cw1, cb1, W + OFF_H1);
  conv2_k<<<512, 256, 0, stream>>>(W + OFF_H1, W + OFF_WT2, cb2, W + OFF_H2);
  // H1 region dead now: build the permuted m1w/m1b there (consumed by gemm128)
  permute_m1<<<10584, 128, 0, stream>>>(m1w, m1b, W + OFF_M1WT, W + OFF_M1BT);
  conv3_k<<<512, 256, 0, stream>>>(W + OFF_H2, W + OFF_WT3, cb3, W + OFF_FEAT);
  // decoder conv weight transposes: [24][24][3][3] -> [ic*9+tap][oc]
  transpose_w<<<(24 * 216 + 255) / 256, 256, 0, stream>>>(c1w, W + OFF_WT2, 24, 216);
  transpose_w<<<(24 * 216 + 255) / 256, 256, 0, stream>>>(c2w, W + OFF_WT3, 24, 216);
  // x = relu(feat @ fcw^T + fcb)  -- split-K x4 (partials in dead OFF_M0)
  gemm_splitk_k<<<dim3(8, 8, 4), 256, 0, stream>>>(W + OFF_FEAT, fcw, W + OFF_M0,
                                                   512, 3136, 784);
  splitk_reduce_k<<<256, 256, 0, stream>>>(W + OFF_M0, fcb, W + OFF_X);
  // heads
  gemm_k<false><<<dim3(1, 8), 256, 0, stream>>>(W + OFF_X, otw, otb, W + OFF_OT, 40, 512);
  gemm_k<false><<<dim3(1, 8), 256, 0, stream>>>(W + OFF_X, ctw, ctb, W + OFF_CT, 2, 512);
  // m0 = x @ m1wT^T + m1bT  -> [b][21][21][24] channel-last directly
  gemm128_k<<<dim3(83, 4), 256, 0, stream>>>(W + OFF_X, W + OFF_M1WT, W + OFF_M1BT,
                                             W + OFF_M0, 10584, 512);
  // decoder (R1 stored channel-last [b][42][42][24])
  upconv1_k<<<512 * 7, 384, 0, stream>>>(W + OFF_M0, W + OFF_WT2, c1b, W + OFF_R1);
  upconv2_final_k<<<512 * 28, 384, 0, stream>>>(W + OFF_R1, inp, W + OFF_WT3, c2b,
                                                c3w, c3b, W + OFF_OT, W + OFF_CT, out);
}